// Round 6
// baseline (379.476 us; speedup 1.0000x reference)
//
#include <hip/hip_runtime.h>
#include <math.h>

#define B 4
#define S 2048
#define E 1024
#define H 64
#define BS (B*S)
#define LOG2E 1.44269504088896f
#define CINIT (-69.2493662f)   // -48 * log2(e): fixed softmax max in log2 domain

typedef float v4f __attribute__((ext_vector_type(4)));
typedef short v8s __attribute__((ext_vector_type(8)));
typedef unsigned short u16;
typedef u16 u16x8 __attribute__((ext_vector_type(8)));
typedef u16 u16x4 __attribute__((ext_vector_type(4)));

#define MFMA(a,b,c) __builtin_amdgcn_mfma_f32_16x16x32_bf16(a,b,c,0,0,0)

// round-half-up fp32 -> bf16
__device__ inline u16 rh_bf16(float x){ return (u16)((__float_as_uint(x)+0x8000u)>>16); }

// ============================================================
// k0: W[E][H] fp32 -> transposed hi/lo bf16 planes Wt[p][h][e].
// p==0 (Wq) pre-scaled by log2(e) so scores land in log2 domain.
// Block 0 also zeroes the split-K fixup counters (stream-ordered
// before attn, re-run every graph replay).
// ============================================================
__global__ __launch_bounds__(256) void wsetup_kernel(
    const float* __restrict__ Wq, const float* __restrict__ Wk,
    const float* __restrict__ Wv,
    u16* __restrict__ Wt_hi, u16* __restrict__ Wt_lo, int* __restrict__ cnt)
{
    __shared__ float wt[64][65];
    const int t  = threadIdx.x;
    const int p  = blockIdx.x >> 4;
    const int e0 = (blockIdx.x & 15) * 64;
    const float* Wsrc = (p==0) ? Wq : (p==1 ? Wk : Wv);
    const float scale = (p==0) ? LOG2E : 1.0f;

    if (blockIdx.x == 0 && t < 128) cnt[t] = 0;

    #pragma unroll
    for (int i=0;i<16;i++){
        int e_l = i*4 + (t>>6);
        wt[e_l][t&63] = Wsrc[(size_t)(e0+e_l)*H + (t&63)] * scale;
    }
    __syncthreads();

    const int h = t>>2, e16 = (t&3)*16;
    u16 hi_a[16], lo_a[16];
    #pragma unroll
    for (int j=0;j<16;j++){
        float f = wt[e16+j][h];
        unsigned u = __float_as_uint(f);
        hi_a[j] = (u16)(u>>16);                       // truncation split
        float hif = __uint_as_float(u & 0xFFFF0000u);
        lo_a[j] = rh_bf16(f - hif);                   // residual to bf16
    }
    u16* dh = Wt_hi + (size_t)(p*64+h)*E + e0 + e16;
    u16* dl = Wt_lo + (size_t)(p*64+h)*E + e0 + e16;
    *(u16x8*)dh     = *(u16x8*)&hi_a[0];
    *(u16x8*)(dh+8) = *(u16x8*)&hi_a[8];
    *(u16x8*)dl     = *(u16x8*)&lo_a[0];
    *(u16x8*)(dl+8) = *(u16x8*)&lo_a[8];
}

// ============================================================
// k1: projections, WAVE-PRIVATE staging, ZERO barriers in main loop.
// block = 256 thr (4 waves): wave wv -> rows (wv>>1)*16..+16, h-half wv&1.
// Each wave stages its own x rows (fp32, padded [16][68]) and its own
// W half (hi/lo, [32][72]) into a private LDS slice: global->reg,
// ds_write, issue next chunk's loads into the SAME regs (WAR-safe:
// ds_write consumes regs at issue), then ds_read/convert/MFMA.
// Waves never rendezvous -> per-wave memory stalls are covered by the
// other independent waves on the CU (8 waves/CU at this LDS size).
// v projection (p==2) transposed in-block, written to vt[b][h][s].
// ============================================================
__global__ __launch_bounds__(256) void proj_kernel(
    const float* __restrict__ query, const float* __restrict__ key_,
    const float* __restrict__ value,
    const u16* __restrict__ Wt_hi, const u16* __restrict__ Wt_lo,
    const float* __restrict__ bq, const float* __restrict__ bk,
    const float* __restrict__ bv,
    u16* __restrict__ q_hi, u16* __restrict__ q_lo,
    u16* __restrict__ k_hi, u16* __restrict__ k_lo,
    u16* __restrict__ vt)
{
    __shared__ __align__(16) float xw[4][16][68];   // wave-private x tiles
    __shared__ __align__(16) u16  whw[4][32][72];   // wave-private W hi
    __shared__ __align__(16) u16  wlw[4][32][72];   // wave-private W lo
    __shared__ __align__(16) u16  vtile[64][40];    // epilogue only

    const int t  = threadIdx.x;
    const int p  = blockIdx.x >> 8;           // 0..2
    const int r0 = (blockIdx.x & 255) * 32;   // global row base (flat [BS])
    const float* xp = (p==0) ? query : (p==1 ? key_ : value);
    const int wv = t>>6, lane = t&63, m = lane&15, quad = lane>>4;
    const int whalf = wv>>1, nh = wv&1;

    // staging addresses (wave-private, coalesced)
    const int sr = lane>>4, sc = (lane&15)*4;   // x: row sr+j*4, col sc
    const float* xgb = xp + (size_t)(r0 + whalf*16 + sr)*E + sc;
    const int wr = lane>>3, wc = (lane&7)*8;    // W: row wr+j*8, col wc
    const u16* whgb = Wt_hi + (size_t)(p*64 + nh*32 + wr)*E + wc;
    const u16* wlgb = Wt_lo + (size_t)(p*64 + nh*32 + wr)*E + wc;

    v4f acc[2];
    acc[0] = (v4f){0.f,0.f,0.f,0.f};
    acc[1] = (v4f){0.f,0.f,0.f,0.f};

    float4 xr_[4];
    u16x8  whr_[4], wlr_[4];

#define LOADG(EC) {                                                            \
        _Pragma("unroll")                                                      \
        for (int j=0;j<4;j++)                                                  \
            xr_[j]  = *(const float4*)(xgb + (size_t)j*4*E + (EC)*64);         \
        _Pragma("unroll")                                                      \
        for (int j=0;j<4;j++)                                                  \
            whr_[j] = *(const u16x8*)(whgb + (size_t)j*8*E + (EC)*64);         \
        _Pragma("unroll")                                                      \
        for (int j=0;j<4;j++)                                                  \
            wlr_[j] = *(const u16x8*)(wlgb + (size_t)j*8*E + (EC)*64);         \
    }

    LOADG(0);
    for (int ec=0; ec<16; ++ec){
        // ---- write current chunk to private LDS (waits vmcnt as needed) ----
        #pragma unroll
        for (int j=0;j<4;j++) *(float4*)&xw[wv][sr + j*4][sc] = xr_[j];
        #pragma unroll
        for (int j=0;j<4;j++) *(u16x8*)&whw[wv][wr + j*8][wc] = whr_[j];
        #pragma unroll
        for (int j=0;j<4;j++) *(u16x8*)&wlw[wv][wr + j*8][wc] = wlr_[j];
        // ---- issue next chunk's loads (regs free after ds_write issue) ----
        if (ec+1 < 16) LOADG(ec+1);
        // ---- consume: ds_read, convert, MFMA (lgkm waits auto) ----
        float fA[16];
        *(float4*)&fA[0]  = *(const float4*)&xw[wv][m][quad*8];
        *(float4*)&fA[4]  = *(const float4*)&xw[wv][m][quad*8+4];
        *(float4*)&fA[8]  = *(const float4*)&xw[wv][m][32+quad*8];
        *(float4*)&fA[12] = *(const float4*)&xw[wv][m][36+quad*8];
        u16 ha[16], la[16];
        #pragma unroll
        for (int j=0;j<16;j++){
            unsigned u = __float_as_uint(fA[j]);
            ha[j] = (u16)(u>>16);
            la[j] = rh_bf16(fA[j] - __uint_as_float(u & 0xFFFF0000u));
        }
        v8s ah0 = *(v8s*)&ha[0], ah1 = *(v8s*)&ha[8];
        v8s al0 = *(v8s*)&la[0], al1 = *(v8s*)&la[8];
        #pragma unroll
        for (int i=0;i<2;i++){
            const int wrl = i*16 + m;
            v8s bh0 = *(const v8s*)&whw[wv][wrl][quad*8];
            v8s bh1 = *(const v8s*)&whw[wv][wrl][32+quad*8];
            v8s bl0 = *(const v8s*)&wlw[wv][wrl][quad*8];
            v8s bl1 = *(const v8s*)&wlw[wv][wrl][32+quad*8];
            v4f d = acc[i];
            d = MFMA(ah0,bh0,d); d = MFMA(ah1,bh1,d);
            d = MFMA(al0,bh0,d); d = MFMA(al1,bh1,d);
            d = MFMA(ah0,bl0,d); d = MFMA(ah1,bl1,d);
            acc[i] = d;
        }
    }
#undef LOADG

    // ---- epilogue ----
    const float* bp = (p==0) ? bq : (p==1 ? bk : bv);
    if (p<2){
        const float bscale = (p==0) ? LOG2E : 1.0f;
        u16* dh = (p==0) ? q_hi : k_hi;
        u16* dl = (p==0) ? q_lo : k_lo;
        #pragma unroll
        for (int i=0;i<2;i++){
            const int hl = nh*32 + i*16 + m;
            const float bb = bp[hl]*bscale;
            #pragma unroll
            for (int r=0;r<4;r++){
                const int gr = r0 + whalf*16 + quad*4 + r;  // D: row = quad*4+reg
                const float val = acc[i][r] + bb;
                unsigned u = __float_as_uint(val);
                u16 hi = (u16)(u>>16);
                float hif = __uint_as_float(u & 0xFFFF0000u);
                u16 lo = rh_bf16(val - hif);
                dh[(size_t)gr*H + hl] = hi;
                dl[(size_t)gr*H + hl] = lo;
            }
        }
    } else {
        // v: bf16 into LDS transposed, then coalesced store to vt[b][h][s]
        const int rlb = whalf*16 + quad*4;
        #pragma unroll
        for (int i=0;i<2;i++){
            const int hl = nh*32 + i*16 + m;
            const float bb = bp[hl];
            u16 vv[4];
            #pragma unroll
            for (int r=0;r<4;r++) vv[r] = rh_bf16(acc[i][r] + bb);
            *(u16x4*)&vtile[hl][rlb] = *(u16x4*)&vv[0];
        }
        __syncthreads();
        const int h = t>>2, so = (t&3)*8;
        const int bidx = r0 >> 11, s0l = r0 & (S-1);
        u16* dst = vt + ((size_t)(bidx*H + h))*S + s0l + so;
        *(u16x8*)dst = *(const u16x8*)&vtile[h][so];
    }
}

// ============================================================
// k3: flash attention, fixed-max softmax (log2 domain), split-K,
// with FUSED split-K fixup: last chunk-block per qb (device atomic
// counter) reduces the K partials (L2-hot) and writes out.
// block = 256 thr (4 waves x 16 q-rows = 64 q-rows), TK=32/iter.
// ============================================================
__global__ __launch_bounds__(256) void attn_kernel(
    const u16* __restrict__ qh_g, const u16* __restrict__ ql_g,
    const u16* __restrict__ kh_g, const u16* __restrict__ kl_g,
    const u16* __restrict__ vt_g,
    float* __restrict__ accw, float* __restrict__ lw,
    float* __restrict__ out, int* __restrict__ cnt, int ksplit)
{
    __shared__ __align__(16) u16 khe[2][16][72];   // [jj&1][jj>>1][h]
    __shared__ __align__(16) u16 kle[2][16][72];
    __shared__ __align__(16) u16 vtl[64][40];      // [h][jj]
    __shared__ __align__(16) u16 pl[4][16][40];    // per-wave P [row][jj]
    __shared__ int lastflag;

    const int t = threadIdx.x;
    const int wv = t>>6, lane = t&63, m = lane&15, quad = lane>>4;
    const int bid = blockIdx.x;
    const int qb = bid / ksplit, chunk = bid % ksplit;
    const int b = qb >> 5, s0 = (qb & 31)*64;
    const int ck = S / ksplit;
    const int j0base = chunk * ck;
    const int iters = ck / 32;

    // persistent q fragments (hi c0/c1, lo c0/c1)
    const u16* qr = qh_g + (size_t)(b*S + s0 + wv*16 + m)*H + quad*8;
    const u16* qrl = ql_g + (size_t)(b*S + s0 + wv*16 + m)*H + quad*8;
    const v8s qh0 = *(const v8s*)(qr),  qh1 = *(const v8s*)(qr+32);
    const v8s ql0 = *(const v8s*)(qrl), ql1 = *(const v8s*)(qrl+32);

    v4f oacc[4];
    #pragma unroll
    for (int nt=0;nt<4;nt++) oacc[nt] = (v4f){0.f,0.f,0.f,0.f};
    float lp[4] = {0.f,0.f,0.f,0.f};
    const v4f cinit = (v4f){CINIT,CINIT,CINIT,CINIT};

    // staging coords
    const int sj = t>>3, sh8 = (t&7)*8;   // K tiles: 32 rows x 64 h
    const u16* khs = kh_g + (size_t)(b*S + j0base + sj)*H + sh8;
    const u16* kls = kl_g + (size_t)(b*S + j0base + sj)*H + sh8;
    u16* khd = &khe[sj&1][sj>>1][sh8];
    u16* kld = &kle[sj&1][sj>>1][sh8];
    const int vh = t>>2, vj8 = (t&3)*8;   // vt tile: 64 h x 32 jj
    const u16* vts = vt_g + (size_t)(b*H + vh)*S + j0base + vj8;
    u16* vtd = &vtl[vh][vj8];

    // ping-pong staging registers
    u16x8 khA, klA, vtA, khB, klB, vtB;
    khA = *(const u16x8*)khs;
    klA = *(const u16x8*)kls;
    vtA = *(const u16x8*)vts;

#define ATTN_ITER(IT, KHC, KLC, VTC, KHN, KLN, VTN, PREF)                      \
    {                                                                          \
        __syncthreads();                                                       \
        *(u16x8*)khd = KHC; *(u16x8*)kld = KLC; *(u16x8*)vtd = VTC;            \
        if (PREF){                                                             \
            KHN = *(const u16x8*)(khs + (size_t)((IT)+1)*32*H);                \
            KLN = *(const u16x8*)(kls + (size_t)((IT)+1)*32*H);                \
            VTN = *(const u16x8*)(vts + ((IT)+1)*32);                          \
        }                                                                      \
        __syncthreads();                                                       \
        /* QK^T: 2 D-tiles x 6 MFMAs (3-term hi/lo), C-init = -m_fix */        \
        v4f sc[2];                                                             \
        _Pragma("unroll")                                                      \
        for (int jt=0;jt<2;jt++){                                              \
            const u16* kr  = &khe[jt][m][quad*8];                              \
            const u16* krl = &kle[jt][m][quad*8];                              \
            v8s b0 = *(const v8s*)kr,  b1 = *(const v8s*)(kr+32);              \
            v8s c0 = *(const v8s*)krl, c1 = *(const v8s*)(krl+32);             \
            v4f d = cinit;                                                     \
            d = MFMA(qh0,b0,d); d = MFMA(qh1,b1,d);                            \
            d = MFMA(ql0,b0,d); d = MFMA(ql1,b1,d);                            \
            d = MFMA(qh0,c0,d); d = MFMA(qh1,c1,d);                            \
            sc[jt] = d;                                                        \
        }                                                                      \
        /* P = exp2(s'), accumulate l, pack bf16 pairs to wave-local LDS */    \
        _Pragma("unroll")                                                      \
        for (int r=0;r<4;r++){                                                 \
            float p0 = exp2f(sc[0][r]);   /* key j0 + 2m   */                  \
            float p1 = exp2f(sc[1][r]);   /* key j0 + 2m+1 */                  \
            lp[r] += p0 + p1;                                                  \
            unsigned pk = ((__float_as_uint(p0)+0x8000u)>>16)                  \
                        | ((__float_as_uint(p1)+0x8000u) & 0xFFFF0000u);       \
            *(unsigned*)&pl[wv][quad*4+r][2*m] = pk;                           \
        }                                                                      \
        /* no barrier: pl[wv] is wave-private, DS ops are in program order */  \
        v8s pa = *(const v8s*)&pl[wv][m][quad*8];                              \
        _Pragma("unroll")                                                      \
        for (int nt=0;nt<4;nt++){                                              \
            v8s vb = *(const v8s*)&vtl[nt*16+m][quad*8];                       \
            oacc[nt] = MFMA(pa, vb, oacc[nt]);                                 \
        }                                                                      \
    }

    for (int it=0; it<iters; it+=2){   // iters = 64/ksplit, always even
        ATTN_ITER(it,   khA,klA,vtA, khB,klB,vtB, true)
        ATTN_ITER(it+1, khB,klB,vtB, khA,klA,vtA, (it+2<iters))
    }
#undef ATTN_ITER

    // ---- epilogue: reduce l across 16 cols, write partials ----
    #pragma unroll
    for (int r=0;r<4;r++){
        float v = lp[r];
        v += __shfl_xor(v,1); v += __shfl_xor(v,2);
        v += __shfl_xor(v,4); v += __shfl_xor(v,8);
        lp[r] = v;
    }
    const int growb = b*S + s0 + wv*16;
    if (m==0){
        float4 lv; lv.x=lp[0]; lv.y=lp[1]; lv.z=lp[2]; lv.w=lp[3];
        *(float4*)(lw + (size_t)chunk*BS + growb + quad*4) = lv;
    }
    float* ab = accw + ((size_t)chunk*BS + growb)*H;
    #pragma unroll
    for (int nt=0;nt<4;nt++){
        #pragma unroll
        for (int r=0;r<4;r++)
            ab[(size_t)(quad*4+r)*H + nt*16 + m] = oacc[nt][r];
    }

    // ---- fused split-K fixup: last block per qb merges partials ----
    __threadfence();
    __syncthreads();
    if (t==0){
        int old = atomicAdd(&cnt[qb], 1);
        lastflag = (old == ksplit-1) ? 1 : 0;
    }
    __syncthreads();
    if (lastflag){
        __threadfence();
        const int rowb = qb*64;
        #pragma unroll
        for (int i=0;i<4;i++){
            const int idx = i*256 + t;               // 64 rows x 16 float4-cols
            const int row = rowb + (idx>>4), h4 = (idx&15)*4;
            float4 a = {0.f,0.f,0.f,0.f};
            float ls = 0.f;
            for (int c=0;c<ksplit;c++){
                const float4 t4 = *(const float4*)(accw + ((size_t)c*BS + row)*H + h4);
                a.x+=t4.x; a.y+=t4.y; a.z+=t4.z; a.w+=t4.w;
                ls += lw[(size_t)c*BS + row];
            }
            const float inv = __builtin_amdgcn_rcpf(ls);
            float4 o; o.x=a.x*inv; o.y=a.y*inv; o.z=a.z*inv; o.w=a.w*inv;
            *(float4*)(out + (size_t)row*H + h4) = o;
        }
    }
}

// ============================================================
extern "C" void kernel_launch(void* const* d_in, const int* in_sizes, int n_in,
                              void* d_out, int out_size, void* d_ws, size_t ws_size,
                              hipStream_t stream) {
    const float* query = (const float*)d_in[0];
    const float* key_  = (const float*)d_in[1];
    const float* value = (const float*)d_in[2];
    const float* Wq    = (const float*)d_in[3];
    const float* bq    = (const float*)d_in[4];
    const float* Wk    = (const float*)d_in[5];
    const float* bk    = (const float*)d_in[6];
    const float* Wv    = (const float*)d_in[7];
    const float* bv    = (const float*)d_in[8];
    float* out = (float*)d_out;

    char* base = (char*)d_ws;
    size_t off = 0;
    u16* Wt_hi = (u16*)(base + off); off += (size_t)3*64*E*2;
    u16* Wt_lo = (u16*)(base + off); off += (size_t)3*64*E*2;
    u16* q_hi  = (u16*)(base + off); off += (size_t)BS*H*2;
    u16* q_lo  = (u16*)(base + off); off += (size_t)BS*H*2;
    u16* k_hi  = (u16*)(base + off); off += (size_t)BS*H*2;
    u16* k_lo  = (u16*)(base + off); off += (size_t)BS*H*2;
    u16* vt    = (u16*)(base + off); off += (size_t)BS*H*2;
    int* cnt   = (int*)(base + off); off += 128*sizeof(int);
    off = (off + 255) & ~(size_t)255;
    const size_t fixed = off;
    const size_t CH = (size_t)BS*H*4 + (size_t)BS*4;  // acc + l per chunk

    int K = 1;
    if      (ws_size >= fixed + 8*CH) K = 8;
    else if (ws_size >= fixed + 4*CH) K = 4;
    else if (ws_size >= fixed + 2*CH) K = 2;

    float* lw   = (float*)(base + fixed);
    float* accw = (float*)(base + fixed + (size_t)K*BS*4);

    wsetup_kernel<<<48, 256, 0, stream>>>(Wq, Wk, Wv, Wt_hi, Wt_lo, cnt);
    proj_kernel<<<768, 256, 0, stream>>>(query, key_, value, Wt_hi, Wt_lo,
                                         bq, bk, bv, q_hi, q_lo, k_hi, k_lo, vt);
    attn_kernel<<<128*K, 256, 0, stream>>>(q_hi, q_lo, k_hi, k_lo, vt,
                                           accw, lw, out, cnt, K);
}

// Round 7
// 164.057 us; speedup vs baseline: 2.3131x; 2.3131x over previous
//
#include <hip/hip_runtime.h>
#include <math.h>

#define B 4
#define S 2048
#define E 1024
#define H 64
#define BS (B*S)
#define LOG2E 1.44269504088896f
#define CINIT (-69.2493662f)   // -48 * log2(e): fixed softmax max in log2 domain

typedef float v4f __attribute__((ext_vector_type(4)));
typedef short v8s __attribute__((ext_vector_type(8)));
typedef unsigned short u16;
typedef u16 u16x8 __attribute__((ext_vector_type(8)));
typedef u16 u16x4 __attribute__((ext_vector_type(4)));

#define MFMA(a,b,c) __builtin_amdgcn_mfma_f32_16x16x32_bf16(a,b,c,0,0,0)

// round-half-up fp32 -> bf16
__device__ inline u16 rh_bf16(float x){ return (u16)((__float_as_uint(x)+0x8000u)>>16); }

// ============================================================
// k0: W[E][H] fp32 -> transposed hi/lo bf16 planes Wt[p][h][e].
// p==0 (Wq) pre-scaled by log2(e) so scores land in log2 domain.
// ============================================================
__global__ __launch_bounds__(256) void wsetup_kernel(
    const float* __restrict__ Wq, const float* __restrict__ Wk,
    const float* __restrict__ Wv,
    u16* __restrict__ Wt_hi, u16* __restrict__ Wt_lo)
{
    __shared__ float wt[64][65];
    const int t  = threadIdx.x;
    const int p  = blockIdx.x >> 4;
    const int e0 = (blockIdx.x & 15) * 64;
    const float* Wsrc = (p==0) ? Wq : (p==1 ? Wk : Wv);
    const float scale = (p==0) ? LOG2E : 1.0f;

    #pragma unroll
    for (int i=0;i<16;i++){
        int e_l = i*4 + (t>>6);
        wt[e_l][t&63] = Wsrc[(size_t)(e0+e_l)*H + (t&63)] * scale;
    }
    __syncthreads();

    const int h = t>>2, e16 = (t&3)*16;
    u16 hi_a[16], lo_a[16];
    #pragma unroll
    for (int j=0;j<16;j++){
        float f = wt[e16+j][h];
        unsigned u = __float_as_uint(f);
        hi_a[j] = (u16)(u>>16);                       // truncation split
        float hif = __uint_as_float(u & 0xFFFF0000u);
        lo_a[j] = rh_bf16(f - hif);                   // residual to bf16
    }
    u16* dh = Wt_hi + (size_t)(p*64+h)*E + e0 + e16;
    u16* dl = Wt_lo + (size_t)(p*64+h)*E + e0 + e16;
    *(u16x8*)dh     = *(u16x8*)&hi_a[0];
    *(u16x8*)(dh+8) = *(u16x8*)&hi_a[8];
    *(u16x8*)dl     = *(u16x8*)&lo_a[0];
    *(u16x8*)(dl+8) = *(u16x8*)&lo_a[8];
}

// ============================================================
// k1: projections via MFMA with hi/lo 3-term products (~fp32 exact).
// block = 256 thr (4 waves) covering 32 rows x 64 h.
//   wave wv: row-half = wv>>1 (16 rows), h-half = wv&1 (2 n-tiles).
// __launch_bounds__(256,3): min 3 waves/EU -> VGPR cap ~170 (was
// default-capped at ~60, which serialized the staging loads; LDS
// already limits blocks/CU, so the old cap bought nothing).
// T14 ping-pong prefetch of next x/W chunk into registers.
// v projection (p==2) transposed in-block, written to vt[b][h][s].
// ============================================================
__global__ __launch_bounds__(256, 3) void proj_kernel(
    const float* __restrict__ query, const float* __restrict__ key_,
    const float* __restrict__ value,
    const u16* __restrict__ Wt_hi, const u16* __restrict__ Wt_lo,
    const float* __restrict__ bq, const float* __restrict__ bk,
    const float* __restrict__ bv,
    u16* __restrict__ q_hi, u16* __restrict__ q_lo,
    u16* __restrict__ k_hi, u16* __restrict__ k_lo,
    u16* __restrict__ vt)
{
    __shared__ __align__(16) u16 xh[32][72], xl[32][72];   // x tile hi/lo
    __shared__ __align__(16) u16 wh[64][72], wl[64][72];   // W^T tile hi/lo
    __shared__ __align__(16) u16 vtile[64][40];            // v transpose staging

    const int t  = threadIdx.x;
    const int p  = blockIdx.x >> 8;           // 0..2
    const int r0 = (blockIdx.x & 255) * 32;   // global row base (flat [BS])
    const float* xp = (p==0) ? query : (p==1 ? key_ : value);
    const int wv = t>>6, lane = t&63, m = lane&15, quad = lane>>4;
    const int whalf = wv>>1, nh = wv&1;

    const int srow = t>>3, se8 = (t&7)*8;     // x staging: 8 fp32/thread
    const int swh  = t>>2, seo  = (t&3)*16;   // W staging: 16 u16/thread/plane

    const float* xb  = xp + (size_t)(r0+srow)*E + se8;
    const u16*   shb = Wt_hi + (size_t)(p*64+swh)*E + seo;
    const u16*   slb = Wt_lo + (size_t)(p*64+swh)*E + seo;

    v4f acc[2];
    acc[0] = (v4f){0.f,0.f,0.f,0.f};
    acc[1] = (v4f){0.f,0.f,0.f,0.f};

    // ping-pong register sets (T14)
    float4 xA[2], xB[2];
    u16x8  wA[4], wB[4];
    xA[0] = *(const float4*)(xb);
    xA[1] = *(const float4*)(xb+4);
    wA[0] = *(const u16x8*)(shb);   wA[1] = *(const u16x8*)(shb+8);
    wA[2] = *(const u16x8*)(slb);   wA[3] = *(const u16x8*)(slb+8);

#define PROJ_ITER(EC, XC, WC, XN, WN, PREF)                                    \
    {                                                                          \
        __syncthreads();                                                       \
        float fv[8] = {XC[0].x,XC[0].y,XC[0].z,XC[0].w,                        \
                       XC[1].x,XC[1].y,XC[1].z,XC[1].w};                       \
        u16 ha[8], la[8];                                                      \
        _Pragma("unroll")                                                      \
        for (int j=0;j<8;j++){                                                 \
            unsigned u = __float_as_uint(fv[j]);                               \
            ha[j] = (u16)(u>>16);                                              \
            la[j] = rh_bf16(fv[j] - __uint_as_float(u & 0xFFFF0000u));         \
        }                                                                      \
        *(u16x8*)&xh[srow][se8] = *(u16x8*)&ha[0];                             \
        *(u16x8*)&xl[srow][se8] = *(u16x8*)&la[0];                             \
        *(u16x8*)&wh[swh][seo]   = WC[0];                                      \
        *(u16x8*)&wh[swh][seo+8] = WC[1];                                      \
        *(u16x8*)&wl[swh][seo]   = WC[2];                                      \
        *(u16x8*)&wl[swh][seo+8] = WC[3];                                      \
        if (PREF){                                                             \
            const float* xn = xb + ((EC)+1)*64;                                \
            XN[0] = *(const float4*)(xn);                                      \
            XN[1] = *(const float4*)(xn+4);                                    \
            const u16* shn = shb + ((EC)+1)*64;                                \
            const u16* sln = slb + ((EC)+1)*64;                                \
            WN[0]=*(const u16x8*)(shn); WN[1]=*(const u16x8*)(shn+8);          \
            WN[2]=*(const u16x8*)(sln); WN[3]=*(const u16x8*)(sln+8);          \
        }                                                                      \
        __syncthreads();                                                       \
        v8s ah0 = *(v8s*)&xh[whalf*16+m][quad*8];                              \
        v8s ah1 = *(v8s*)&xh[whalf*16+m][32+quad*8];                           \
        v8s al0 = *(v8s*)&xl[whalf*16+m][quad*8];                              \
        v8s al1 = *(v8s*)&xl[whalf*16+m][32+quad*8];                           \
        _Pragma("unroll")                                                      \
        for (int i=0;i<2;i++){                                                 \
            const int nt = nh*2+i;                                             \
            v8s bh0 = *(v8s*)&wh[nt*16+m][quad*8];                             \
            v8s bh1 = *(v8s*)&wh[nt*16+m][32+quad*8];                          \
            v8s bl0 = *(v8s*)&wl[nt*16+m][quad*8];                             \
            v8s bl1 = *(v8s*)&wl[nt*16+m][32+quad*8];                          \
            v4f d = acc[i];                                                    \
            d = MFMA(ah0,bh0,d); d = MFMA(ah1,bh1,d);                          \
            d = MFMA(al0,bh0,d); d = MFMA(al1,bh1,d);                          \
            d = MFMA(ah0,bl0,d); d = MFMA(ah1,bl1,d);                          \
            acc[i] = d;                                                        \
        }                                                                      \
    }

    for (int ec2=0; ec2<16; ec2+=2){
        PROJ_ITER(ec2,   xA, wA, xB, wB, true)
        PROJ_ITER(ec2+1, xB, wB, xA, wA, (ec2<14))
    }
#undef PROJ_ITER

    // ---- epilogue ----
    const float* bp = (p==0) ? bq : (p==1 ? bk : bv);
    if (p<2){
        const float bscale = (p==0) ? LOG2E : 1.0f;
        u16* dh = (p==0) ? q_hi : k_hi;
        u16* dl = (p==0) ? q_lo : k_lo;
        #pragma unroll
        for (int i=0;i<2;i++){
            const int hl = (nh*2+i)*16+m;
            const float bb = bp[hl]*bscale;
            #pragma unroll
            for (int r=0;r<4;r++){
                const int gr = r0 + whalf*16 + quad*4 + r;  // D: row = quad*4+reg
                const float val = acc[i][r] + bb;
                unsigned u = __float_as_uint(val);
                u16 hi = (u16)(u>>16);
                float hif = __uint_as_float(u & 0xFFFF0000u);
                u16 lo = rh_bf16(val - hif);
                dh[(size_t)gr*H + hl] = hi;
                dl[(size_t)gr*H + hl] = lo;
            }
        }
    } else {
        // v: bf16 into LDS transposed, then coalesced store to vt[b][h][s]
        const int rlb = whalf*16 + quad*4;
        #pragma unroll
        for (int i=0;i<2;i++){
            const int hl = (nh*2+i)*16+m;
            const float bb = bp[hl];
            u16 vv[4];
            #pragma unroll
            for (int r=0;r<4;r++) vv[r] = rh_bf16(acc[i][r] + bb);
            *(u16x4*)&vtile[hl][rlb] = *(u16x4*)&vv[0];
        }
        __syncthreads();
        const int h = t>>2, so = (t&3)*8;
        const int bidx = r0 >> 11, s0l = r0 & (S-1);
        u16* dst = vt + ((size_t)(bidx*H + h))*S + s0l + so;
        *(u16x8*)dst = *(const u16x8*)&vtile[h][so];
    }
}

// ============================================================
// k3: flash attention, fixed-max softmax (log2 domain), split-K.
// block = 256 thr (4 waves x 16 q-rows = 64 q-rows), TK=32/iter.
// __launch_bounds__(256,4): VGPR cap 128 (was default-capped ~72).
// T14 ping-pong: next tile's K-hi/K-lo/Vt loads issued into the other
// register set before the compute barrier. pl[wv] is wave-private,
// so no barrier between P-write and PV.
// ============================================================
__global__ __launch_bounds__(256, 4) void attn_kernel(
    const u16* __restrict__ qh_g, const u16* __restrict__ ql_g,
    const u16* __restrict__ kh_g, const u16* __restrict__ kl_g,
    const u16* __restrict__ vt_g,
    float* __restrict__ accw, float* __restrict__ lw, int ksplit)
{
    __shared__ __align__(16) u16 khe[2][16][72];   // [jj&1][jj>>1][h]
    __shared__ __align__(16) u16 kle[2][16][72];
    __shared__ __align__(16) u16 vtl[64][40];      // [h][jj]
    __shared__ __align__(16) u16 pl[4][16][40];    // per-wave P [row][jj]

    const int t = threadIdx.x;
    const int wv = t>>6, lane = t&63, m = lane&15, quad = lane>>4;
    const int bid = blockIdx.x;
    const int qb = bid / ksplit, chunk = bid % ksplit;
    const int b = qb >> 5, s0 = (qb & 31)*64;
    const int ck = S / ksplit;
    const int j0base = chunk * ck;
    const int iters = ck / 32;

    // persistent q fragments (hi c0/c1, lo c0/c1)
    const u16* qr = qh_g + (size_t)(b*S + s0 + wv*16 + m)*H + quad*8;
    const u16* qrl = ql_g + (size_t)(b*S + s0 + wv*16 + m)*H + quad*8;
    const v8s qh0 = *(const v8s*)(qr),  qh1 = *(const v8s*)(qr+32);
    const v8s ql0 = *(const v8s*)(qrl), ql1 = *(const v8s*)(qrl+32);

    v4f oacc[4];
    #pragma unroll
    for (int nt=0;nt<4;nt++) oacc[nt] = (v4f){0.f,0.f,0.f,0.f};
    float lp[4] = {0.f,0.f,0.f,0.f};
    const v4f cinit = (v4f){CINIT,CINIT,CINIT,CINIT};

    // staging coords
    const int sj = t>>3, sh8 = (t&7)*8;   // K tiles: 32 rows x 64 h
    const u16* khs = kh_g + (size_t)(b*S + j0base + sj)*H + sh8;
    const u16* kls = kl_g + (size_t)(b*S + j0base + sj)*H + sh8;
    u16* khd = &khe[sj&1][sj>>1][sh8];
    u16* kld = &kle[sj&1][sj>>1][sh8];
    const int vh = t>>2, vj8 = (t&3)*8;   // vt tile: 64 h x 32 jj
    const u16* vts = vt_g + (size_t)(b*H + vh)*S + j0base + vj8;
    u16* vtd = &vtl[vh][vj8];

    // ping-pong staging registers (T14)
    u16x8 khA, klA, vtA, khB, klB, vtB;
    khA = *(const u16x8*)khs;
    klA = *(const u16x8*)kls;
    vtA = *(const u16x8*)vts;

#define ATTN_ITER(IT, KHC, KLC, VTC, KHN, KLN, VTN, PREF)                      \
    {                                                                          \
        __syncthreads();                                                       \
        *(u16x8*)khd = KHC; *(u16x8*)kld = KLC; *(u16x8*)vtd = VTC;            \
        if (PREF){                                                             \
            KHN = *(const u16x8*)(khs + (size_t)((IT)+1)*32*H);                \
            KLN = *(const u16x8*)(kls + (size_t)((IT)+1)*32*H);                \
            VTN = *(const u16x8*)(vts + ((IT)+1)*32);                          \
        }                                                                      \
        __syncthreads();                                                       \
        /* QK^T: 2 D-tiles x 6 MFMAs (3-term hi/lo), C-init = -m_fix */        \
        v4f sc[2];                                                             \
        _Pragma("unroll")                                                      \
        for (int jt=0;jt<2;jt++){                                              \
            const u16* kr  = &khe[jt][m][quad*8];                              \
            const u16* krl = &kle[jt][m][quad*8];                              \
            v8s b0 = *(const v8s*)kr,  b1 = *(const v8s*)(kr+32);              \
            v8s c0 = *(const v8s*)krl, c1 = *(const v8s*)(krl+32);             \
            v4f d = cinit;                                                     \
            d = MFMA(qh0,b0,d); d = MFMA(qh1,b1,d);                            \
            d = MFMA(ql0,b0,d); d = MFMA(ql1,b1,d);                            \
            d = MFMA(qh0,c0,d); d = MFMA(qh1,c1,d);                            \
            sc[jt] = d;                                                        \
        }                                                                      \
        /* P = exp2(s'), accumulate l, pack bf16 pairs to wave-local LDS */    \
        _Pragma("unroll")                                                      \
        for (int r=0;r<4;r++){                                                 \
            float p0 = exp2f(sc[0][r]);   /* key j0 + 2m   */                  \
            float p1 = exp2f(sc[1][r]);   /* key j0 + 2m+1 */                  \
            lp[r] += p0 + p1;                                                  \
            unsigned pk = ((__float_as_uint(p0)+0x8000u)>>16)                  \
                        | ((__float_as_uint(p1)+0x8000u) & 0xFFFF0000u);       \
            *(unsigned*)&pl[wv][quad*4+r][2*m] = pk;                           \
        }                                                                      \
        /* no barrier: pl[wv] is wave-private, DS ops are in program order */  \
        v8s pa = *(const v8s*)&pl[wv][m][quad*8];                              \
        _Pragma("unroll")                                                      \
        for (int nt=0;nt<4;nt++){                                              \
            v8s vb = *(const v8s*)&vtl[nt*16+m][quad*8];                       \
            oacc[nt] = MFMA(pa, vb, oacc[nt]);                                 \
        }                                                                      \
    }

    for (int it=0; it<iters; it+=2){   // iters = 64/ksplit, always even
        ATTN_ITER(it,   khA,klA,vtA, khB,klB,vtB, true)
        ATTN_ITER(it+1, khB,klB,vtB, khA,klA,vtA, (it+2<iters))
    }
#undef ATTN_ITER

    // ---- epilogue: reduce l across 16 cols, write partials ----
    #pragma unroll
    for (int r=0;r<4;r++){
        float v = lp[r];
        v += __shfl_xor(v,1); v += __shfl_xor(v,2);
        v += __shfl_xor(v,4); v += __shfl_xor(v,8);
        lp[r] = v;
    }
    const int growb = b*S + s0 + wv*16;
    if (m==0){
        float4 lv; lv.x=lp[0]; lv.y=lp[1]; lv.z=lp[2]; lv.w=lp[3];
        *(float4*)(lw + (size_t)chunk*BS + growb + quad*4) = lv;
    }
    float* ab = accw + ((size_t)chunk*BS + growb)*H;
    #pragma unroll
    for (int nt=0;nt<4;nt++){
        #pragma unroll
        for (int r=0;r<4;r++)
            ab[(size_t)(quad*4+r)*H + nt*16 + m] = oacc[nt][r];
    }
}

// ============================================================
// k4: merge split-K partials: out = sum_c acc / sum_c l
// ============================================================
__global__ __launch_bounds__(256) void merge_kernel(
    const float* __restrict__ accw, const float* __restrict__ lw,
    float* __restrict__ out, int ksplit)
{
    const int idx = blockIdx.x*256 + threadIdx.x;
    const int row = idx >> 4, h4 = (idx & 15)*4;
    float4 a = {0.f,0.f,0.f,0.f};
    float ls = 0.f;
    for (int c=0;c<ksplit;c++){
        const float4 t4 = *(const float4*)(accw + ((size_t)c*BS + row)*H + h4);
        a.x+=t4.x; a.y+=t4.y; a.z+=t4.z; a.w+=t4.w;
        ls += lw[(size_t)c*BS + row];
    }
    const float inv = __builtin_amdgcn_rcpf(ls);
    float4 o; o.x=a.x*inv; o.y=a.y*inv; o.z=a.z*inv; o.w=a.w*inv;
    *(float4*)(out + (size_t)row*H + h4) = o;
}

// ============================================================
extern "C" void kernel_launch(void* const* d_in, const int* in_sizes, int n_in,
                              void* d_out, int out_size, void* d_ws, size_t ws_size,
                              hipStream_t stream) {
    const float* query = (const float*)d_in[0];
    const float* key_  = (const float*)d_in[1];
    const float* value = (const float*)d_in[2];
    const float* Wq    = (const float*)d_in[3];
    const float* bq    = (const float*)d_in[4];
    const float* Wk    = (const float*)d_in[5];
    const float* bk    = (const float*)d_in[6];
    const float* Wv    = (const float*)d_in[7];
    const float* bv    = (const float*)d_in[8];
    float* out = (float*)d_out;

    char* base = (char*)d_ws;
    size_t off = 0;
    u16* Wt_hi = (u16*)(base + off); off += (size_t)3*64*E*2;
    u16* Wt_lo = (u16*)(base + off); off += (size_t)3*64*E*2;
    u16* q_hi  = (u16*)(base + off); off += (size_t)BS*H*2;
    u16* q_lo  = (u16*)(base + off); off += (size_t)BS*H*2;
    u16* k_hi  = (u16*)(base + off); off += (size_t)BS*H*2;
    u16* k_lo  = (u16*)(base + off); off += (size_t)BS*H*2;
    u16* vt    = (u16*)(base + off); off += (size_t)BS*H*2;
    const size_t fixed = off;
    const size_t CH = (size_t)BS*H*4 + (size_t)BS*4;  // acc + l per chunk

    int K = 1;
    if      (ws_size >= fixed + 8*CH) K = 8;
    else if (ws_size >= fixed + 4*CH) K = 4;
    else if (ws_size >= fixed + 2*CH) K = 2;

    float* lw   = (float*)(base + fixed);
    float* accw = (float*)(base + fixed + (size_t)K*BS*4);

    wsetup_kernel<<<48, 256, 0, stream>>>(Wq, Wk, Wv, Wt_hi, Wt_lo);
    proj_kernel<<<768, 256, 0, stream>>>(query, key_, value, Wt_hi, Wt_lo,
                                         bq, bk, bv, q_hi, q_lo, k_hi, k_lo, vt);
    attn_kernel<<<128*K, 256, 0, stream>>>(q_hi, q_lo, k_hi, k_lo, vt, accw, lw, K);
    merge_kernel<<<512, 256, 0, stream>>>(accw, lw, out, K);
}